// Round 10
// baseline (106.643 us; speedup 1.0000x reference)
//
#include <hip/hip_runtime.h>
#include <math.h>

#define B_SZ 64
#define SEQ 2048
#define DM 12
#define DI 24
#define DS 16
#define DC 4
#define DTR 4
#define NSEG 32
#define SEGLEN 64
#define LP 68   /* 272 B rows: float4-aligned, 4-bank skew per row */

#define LOG2E 1.4426950408889634f

#if defined(__has_builtin)
#if __has_builtin(__builtin_amdgcn_exp2f)
#define EXP2F(x) __builtin_amdgcn_exp2f(x)
#else
#define EXP2F(x) exp2f(x)
#endif
#else
#define EXP2F(x) exp2f(x)
#endif

typedef float f32x2 __attribute__((ext_vector_type(2)));

__device__ __forceinline__ f32x2 mk2(float a, float b) {
    f32x2 v; v.x = a; v.y = b; return v;
}
// packed fp32: 2 FMAs / 2 MULs / 2 ADDs per instruction (VOP3P)
__device__ __forceinline__ f32x2 pk_fma(f32x2 a, f32x2 b, f32x2 c) {
    asm("v_pk_fma_f32 %0, %1, %2, %0" : "+v"(c) : "v"(a), "v"(b));
    return c;
}
__device__ __forceinline__ f32x2 pk_mul(f32x2 a, f32x2 b) {
    f32x2 d;
    asm("v_pk_mul_f32 %0, %1, %2" : "=v"(d) : "v"(a), "v"(b));
    return d;
}
__device__ __forceinline__ f32x2 pk_add(f32x2 a, f32x2 b) {
    f32x2 d;
    asm("v_pk_add_f32 %0, %1, %2" : "=v"(d) : "v"(a), "v"(b));
    return d;
}

__device__ __forceinline__ float silu_f(float v) {
    return v / (1.f + EXP2F(v * -LOG2E));
}
__device__ __forceinline__ float softplus_f(float v) {
    return fmaxf(v, 0.f) + __logf(1.f + EXP2F(-fabsf(v) * LOG2E));
}
__device__ __forceinline__ float dot12_pk(float4 w0, float4 w1, float4 w2,
                                          float4 r0, float4 r1, float4 r2) {
    f32x2 acc = mk2(0.f, 0.f);
    acc = pk_fma(mk2(w0.x, w0.y), mk2(r0.x, r0.y), acc);
    acc = pk_fma(mk2(w0.z, w0.w), mk2(r0.z, r0.w), acc);
    acc = pk_fma(mk2(w1.x, w1.y), mk2(r1.x, r1.y), acc);
    acc = pk_fma(mk2(w1.z, w1.w), mk2(r1.z, r1.w), acc);
    acc = pk_fma(mk2(w2.x, w2.y), mk2(r2.x, r2.y), acc);
    acc = pk_fma(mk2(w2.z, w2.w), mk2(r2.z, r2.w), acc);
    return acc.x + acc.y;
}

// One block = 2 waves per (batch, segment); grid = 2048.
// Projection phases + scan vector ops use packed-fp32 (v_pk_*) to halve
// VALU instruction count; serial ba-chain + exp2 remain scalar.
__global__ __launch_bounds__(128) void fused2_kernel(
    const float* __restrict__ x, const float* __restrict__ ipw,
    const float* __restrict__ cw, const float* __restrict__ cb,
    const float* __restrict__ xpw, const float* __restrict__ dpw,
    const float* __restrict__ dpb, const float* __restrict__ A_log,
    float* __restrict__ segA, float* __restrict__ segB)
{
    __shared__ __align__(16) float dtxc_s[DI][LP];   // xc (A2->B), then dt (C->scan)
    __shared__ __align__(16) float duxin_s[DI][LP];  // xin (A->A2), then du (C->scan)
    __shared__ __align__(16) float Bs_s[DS][LP];
    __shared__ __align__(16) float dtr_s[DTR][LP];

    const int tid = threadIdx.x;
    const int b = blockIdx.x >> 5, seg = blockIdx.x & 31;
    const int t0 = seg * SEGLEN;
    const int t = tid & 63;
    const int half_u = __builtin_amdgcn_readfirstlane(tid >> 6);  // wave-uniform
    const int dlo = half_u * 12;
    const int olo = 12 - dlo;        // other half's channel base

    // ---- A_log loads issued EARLY; consumed only in the scan ----
    float Ap2[3];
#pragma unroll
    for (int p = 0; p < 3; ++p)
        Ap2[p] = -__expf(A_log[128 * p + tid]) * LOG2E;   // (8p+dq)*16+s == 128p+tid

    // ---- Phase A0: conv halo — 72 (halo-row, channel) units over 128 threads ----
    if (tid < 3 * DI) {
        int hr = tid / DI, d = tid % DI;
        int row = t0 - 3 + hr;
        float v = 0.f;
        if (row >= 0) {
            const float4* xp = (const float4*)(x + ((size_t)b * SEQ + row) * DM);
            const float4* wp = (const float4*)(ipw + d * DM);
            v = dot12_pk(wp[0], wp[1], wp[2], xp[0], xp[1], xp[2]);
        }
        duxin_s[d][hr] = v;
    }

    // ---- Phase A1: xin = in_proj(x_t) for own 12 channels (uniform weights) ----
    {
        const float4* xp = (const float4*)(x + ((size_t)b * SEQ + (t0 + t)) * DM);
        float4 r0 = xp[0], r1 = xp[1], r2 = xp[2];
#pragma unroll 4
        for (int i = 0; i < 12; ++i) {
            const float4* wp = (const float4*)(ipw + (dlo + i) * DM);
            duxin_s[dlo + i][t + 3] = dot12_pk(wp[0], wp[1], wp[2], r0, r1, r2);
        }
    }
    __syncthreads();

    // ---- Phase A2: causal conv + silu for own 12 channels ----
    float xc_reg[12];
#pragma unroll 4
    for (int i = 0; i < 12; ++i) {
        int d = dlo + i;
        const float4 c4 = *(const float4*)(cw + d * DC);
        float acc = cb[d];
        acc = fmaf(c4.x, duxin_s[d][t + 0], acc);
        acc = fmaf(c4.y, duxin_s[d][t + 1], acc);
        acc = fmaf(c4.z, duxin_s[d][t + 2], acc);
        acc = fmaf(c4.w, duxin_s[d][t + 3], acc);
        float v = silu_f(acc);
        xc_reg[i] = v;
        dtxc_s[d][t] = v;
    }
    __syncthreads();

    // ---- Phase B: x_proj rows 10*half..10*half+9 (packed fp32) ----
    {
        f32x2 xc2[12];
#pragma unroll
        for (int i = 0; i < 6; ++i)
            xc2[(dlo >> 1) + i] = mk2(xc_reg[2 * i], xc_reg[2 * i + 1]);
#pragma unroll
        for (int i = 0; i < 6; ++i) {
            int c = (olo >> 1) + i;
            xc2[c] = mk2(dtxc_s[2 * c][t], dtxc_s[2 * c + 1][t]);
        }
#pragma unroll 2
        for (int q = 0; q < 10; ++q) {
            int r = half_u * 10 + q;                 // wave-uniform row
            const float4* wr = (const float4*)(xpw + r * DI);
            f32x2 acc = mk2(0.f, 0.f);
#pragma unroll
            for (int c = 0; c < 6; ++c) {
                float4 w4 = wr[c];
                acc = pk_fma(mk2(w4.x, w4.y), xc2[2 * c], acc);
                acc = pk_fma(mk2(w4.z, w4.w), xc2[2 * c + 1], acc);
            }
            float s = acc.x + acc.y;
            if (r < DTR) dtr_s[r][t] = s;
            else         Bs_s[r - DTR][t] = s;
        }
    }
    __syncthreads();

    // ---- Phase C: dt = softplus(dt_raw @ dpw^T + dpb); dt,du -> LDS ----
    {
        f32x2 q01 = mk2(dtr_s[0][t], dtr_s[1][t]);
        f32x2 q23 = mk2(dtr_s[2][t], dtr_s[3][t]);
#pragma unroll 4
        for (int i = 0; i < 12; ++i) {
            int d = dlo + i;
            const float4 w4 = *(const float4*)(dpw + d * DTR);
            f32x2 acc = mk2(dpb[d], 0.f);
            acc = pk_fma(mk2(w4.x, w4.y), q01, acc);
            acc = pk_fma(mk2(w4.z, w4.w), q23, acc);
            float dt = softplus_f(acc.x + acc.y);
            dtxc_s[d][t] = dt;               // overwrites xc (dead after B)
            duxin_s[d][t] = dt * xc_reg[i];  // du (xin dead after A2)
        }
    }
    __syncthreads();

    // ---- Scan: 3 pairs × 2 independent 32-step half-chains; pk for mul/add ----
    {
        const int s_ = tid & 15;
        const int dq = tid >> 4;             // 0..7 across both waves
        f32x2 sdtL[3], sdtH[3];
        float baL[3], baH[3];
        f32x2 Apv[3];
#pragma unroll
        for (int p = 0; p < 3; ++p) {
            sdtL[p] = mk2(0.f, 0.f); sdtH[p] = mk2(0.f, 0.f);
            baL[p] = 0.f; baH[p] = 0.f;
            Apv[p] = mk2(Ap2[p], Ap2[p]);
        }
        const float* dt_r0 = &dtxc_s[dq][0];
        const float* du_r0 = &duxin_s[dq][0];
#pragma unroll 2
        for (int i = 0; i < 8; ++i) {
            const float4 BL = *(const float4*)&Bs_s[s_][4 * i];
            const float4 BH = *(const float4*)&Bs_s[s_][32 + 4 * i];
            const f32x2 BLlo = mk2(BL.x, BL.y), BLhi = mk2(BL.z, BL.w);
            const f32x2 BHlo = mk2(BH.x, BH.y), BHhi = mk2(BH.z, BH.w);
#pragma unroll
            for (int p = 0; p < 3; ++p) {
                const float4 dL = *(const float4*)(dt_r0 + p * 8 * LP + 4 * i);
                const float4 dH = *(const float4*)(dt_r0 + p * 8 * LP + 32 + 4 * i);
                const float4 uL = *(const float4*)(du_r0 + p * 8 * LP + 4 * i);
                const float4 uH = *(const float4*)(du_r0 + p * 8 * LP + 32 + 4 * i);
                const f32x2 dLlo = mk2(dL.x, dL.y), dLhi = mk2(dL.z, dL.w);
                const f32x2 dHlo = mk2(dH.x, dH.y), dHhi = mk2(dH.z, dH.w);
                f32x2 aL1 = pk_mul(dLlo, Apv[p]), aL2 = pk_mul(dLhi, Apv[p]);
                f32x2 aH1 = pk_mul(dHlo, Apv[p]), aH2 = pk_mul(dHhi, Apv[p]);
                f32x2 uBL1 = pk_mul(mk2(uL.x, uL.y), BLlo);
                f32x2 uBL2 = pk_mul(mk2(uL.z, uL.w), BLhi);
                f32x2 uBH1 = pk_mul(mk2(uH.x, uH.y), BHlo);
                f32x2 uBH2 = pk_mul(mk2(uH.z, uH.w), BHhi);
                float a;
                a = EXP2F(aL1.x); baL[p] = fmaf(a, baL[p], uBL1.x);
                a = EXP2F(aH1.x); baH[p] = fmaf(a, baH[p], uBH1.x);
                a = EXP2F(aL1.y); baL[p] = fmaf(a, baL[p], uBL1.y);
                a = EXP2F(aH1.y); baH[p] = fmaf(a, baH[p], uBH1.y);
                a = EXP2F(aL2.x); baL[p] = fmaf(a, baL[p], uBL2.x);
                a = EXP2F(aH2.x); baH[p] = fmaf(a, baH[p], uBH2.x);
                a = EXP2F(aL2.y); baL[p] = fmaf(a, baL[p], uBL2.y);
                a = EXP2F(aH2.y); baH[p] = fmaf(a, baH[p], uBH2.y);
                sdtL[p] = pk_add(sdtL[p], dLlo); sdtL[p] = pk_add(sdtL[p], dLhi);
                sdtH[p] = pk_add(sdtH[p], dHlo); sdtH[p] = pk_add(sdtH[p], dHhi);
            }
        }
        // compose: lo (t=0..31) then hi (t=32..63)
        const size_t base = (size_t)blockIdx.x * (DI * DS);
#pragma unroll
        for (int p = 0; p < 3; ++p) {
            float sL = sdtL[p].x + sdtL[p].y;
            float sH = sdtH[p].x + sdtH[p].y;
            float aH = EXP2F(Ap2[p] * sH);
            segA[base + 128 * p + tid] = EXP2F(Ap2[p] * (sL + sH));
            segB[base + 128 * p + tid] = fmaf(aH, baL[p], baH[p]);
        }
    }
}

// One block per batch: combine 32 segments + tiny epilogue.
__global__ __launch_bounds__(384) void finish_kernel(
    const float* __restrict__ segA, const float* __restrict__ segB,
    const float* __restrict__ x, const float* __restrict__ ipw,
    const float* __restrict__ cw, const float* __restrict__ cb,
    const float* __restrict__ xpw, const float* __restrict__ Dv,
    const float* __restrict__ opw, const float* __restrict__ fcw,
    const float* __restrict__ fcb, float* __restrict__ out)
{
    int b = blockIdx.x, tid = threadIdx.x;

    float h = 0.f;
#pragma unroll
    for (int g = 0; g < NSEG; ++g) {
        size_t o = ((size_t)(b * NSEG + g)) * (DI * DS) + tid;
        h = fmaf(segA[o], h, segB[o]);
    }

    __shared__ float h_sh[DI * DS];
    __shared__ float xcl[DI], CL[DS], zv[DI], yv[DI], ov[DM];
    h_sh[tid] = h;

    const float* xr = x + ((size_t)b * SEQ + SEQ - 1) * DM;
    if (tid < DI) {
        float acc = cb[tid];
#pragma unroll
        for (int k = 0; k < DC; ++k) {
            const float* row = x + ((size_t)b * SEQ + (SEQ - DC + k)) * DM;
            float xin = 0.f;
#pragma unroll
            for (int m = 0; m < DM; ++m) xin = fmaf(row[m], ipw[tid * DM + m], xin);
            acc = fmaf(xin, cw[tid * DC + k], acc);
        }
        xcl[tid] = silu_f(acc);
        float s = 0.f;
#pragma unroll
        for (int m = 0; m < DM; ++m) s = fmaf(xr[m], ipw[(DI + tid) * DM + m], s);
        zv[tid] = s;
    }
    __syncthreads();

    if (tid < DS) {
        float s = 0.f;
#pragma unroll
        for (int d = 0; d < DI; ++d) s = fmaf(xcl[d], xpw[(DTR + DS + tid) * DI + d], s);
        CL[tid] = s;
    }
    __syncthreads();

    if (tid < DI) {
        float y = 0.f;
#pragma unroll
        for (int s2 = 0; s2 < DS; ++s2) y = fmaf(h_sh[tid * DS + s2], CL[s2], y);
        y = fmaf(xcl[tid], Dv[tid], y);
        yv[tid] = y * silu_f(zv[tid]);
    }
    __syncthreads();

    if (tid < DM) {
        float s = 0.f;
#pragma unroll
        for (int d = 0; d < DI; ++d) s = fmaf(yv[d], opw[tid * DI + d], s);
        ov[tid] = s;
    }
    __syncthreads();

    if (tid == 0) {
        float s = fcb[0];
#pragma unroll
        for (int e = 0; e < DM; ++e) s = fmaf(ov[e], fcw[e], s);
        out[b] = s;
    }
}

extern "C" void kernel_launch(void* const* d_in, const int* in_sizes, int n_in,
                              void* d_out, int out_size, void* d_ws, size_t ws_size,
                              hipStream_t stream)
{
    const float* x   = (const float*)d_in[0];
    const float* ipw = (const float*)d_in[1];
    const float* cw  = (const float*)d_in[2];
    const float* cb  = (const float*)d_in[3];
    const float* xpw = (const float*)d_in[4];
    const float* dpw = (const float*)d_in[5];
    const float* dpb = (const float*)d_in[6];
    const float* Al  = (const float*)d_in[7];
    const float* Dv  = (const float*)d_in[8];
    const float* opw = (const float*)d_in[9];
    const float* fcw = (const float*)d_in[10];
    const float* fcb = (const float*)d_in[11];

    float* segA = (float*)d_ws;                            // [B*NSEG][384]
    float* segB = segA + (size_t)B_SZ * NSEG * DI * DS;

    fused2_kernel<<<B_SZ * NSEG, 128, 0, stream>>>(
        x, ipw, cw, cb, xpw, dpw, dpb, Al, segA, segB);
    finish_kernel<<<B_SZ, 384, 0, stream>>>(
        segA, segB, x, ipw, cw, cb, xpw, Dv, opw, fcw, fcb, (float*)d_out);
}

// Round 11
// 101.785 us; speedup vs baseline: 1.0477x; 1.0477x over previous
//
#include <hip/hip_runtime.h>
#include <math.h>

#define B_SZ 64
#define SEQ 2048
#define DM 12
#define DI 24
#define DS 16
#define DC 4
#define DTR 4
#define NSEG 32
#define SEGLEN 64
#define LP 68   /* 272 B rows: float4-aligned, 4-bank skew per row */

#define LOG2E 1.4426950408889634f

#if defined(__has_builtin)
#if __has_builtin(__builtin_amdgcn_exp2f)
#define EXP2F(x) __builtin_amdgcn_exp2f(x)
#else
#define EXP2F(x) exp2f(x)
#endif
#else
#define EXP2F(x) exp2f(x)
#endif

__device__ __forceinline__ float silu_f(float v) {
    return v / (1.f + EXP2F(v * -LOG2E));
}
__device__ __forceinline__ float softplus_f(float v) {
    return fmaxf(v, 0.f) + __logf(1.f + EXP2F(-fabsf(v) * LOG2E));
}
__device__ __forceinline__ float dot12w(float4 w0, float4 w1, float4 w2,
                                        float4 r0, float4 r1, float4 r2) {
    float s = 0.f;
    s = fmaf(w0.x, r0.x, s); s = fmaf(w0.y, r0.y, s);
    s = fmaf(w0.z, r0.z, s); s = fmaf(w0.w, r0.w, s);
    s = fmaf(w1.x, r1.x, s); s = fmaf(w1.y, r1.y, s);
    s = fmaf(w1.z, r1.z, s); s = fmaf(w1.w, r1.w, s);
    s = fmaf(w2.x, r2.x, s); s = fmaf(w2.y, r2.y, s);
    s = fmaf(w2.z, r2.z, s); s = fmaf(w2.w, r2.w, s);
    return s;
}

// One block = 2 waves per (batch, segment); grid = 2048.
// Scan: each of the thread's 3 (d,s) pairs runs as TWO independent 32-step
// half-chains (6-way ILP), composed in-register via the sum-dt identity.
__global__ __launch_bounds__(128) void fused2_kernel(
    const float* __restrict__ x, const float* __restrict__ ipw,
    const float* __restrict__ cw, const float* __restrict__ cb,
    const float* __restrict__ xpw, const float* __restrict__ dpw,
    const float* __restrict__ dpb, const float* __restrict__ A_log,
    float* __restrict__ segA, float* __restrict__ segB)
{
    __shared__ __align__(16) float dtxc_s[DI][LP];   // xc (A2->B), then dt (C->scan)
    __shared__ __align__(16) float duxin_s[DI][LP];  // xin (A->A2), then du (C->scan)
    __shared__ __align__(16) float Bs_s[DS][LP];
    __shared__ __align__(16) float dtr_s[DTR][LP];

    const int tid = threadIdx.x;
    const int b = blockIdx.x >> 5, seg = blockIdx.x & 31;
    const int t0 = seg * SEGLEN;
    const int t = tid & 63;
    const int half_u = __builtin_amdgcn_readfirstlane(tid >> 6);  // wave-uniform
    const int dlo = half_u * 12;
    const int olo = 12 - dlo;        // other half's channel base

    // ---- A_log loads issued EARLY; results consumed only in the scan ----
    float Ap2[3];
#pragma unroll
    for (int p = 0; p < 3; ++p)
        Ap2[p] = -__expf(A_log[128 * p + tid]) * LOG2E;   // (8p+dq)*16+s == 128p+tid

    // ---- Phase A0: conv halo — 72 (halo-row, channel) units over 128 threads ----
    if (tid < 3 * DI) {
        int hr = tid / DI, d = tid % DI;
        int row = t0 - 3 + hr;
        float v = 0.f;
        if (row >= 0) {
            const float4* xp = (const float4*)(x + ((size_t)b * SEQ + row) * DM);
            const float4* wp = (const float4*)(ipw + d * DM);
            v = dot12w(wp[0], wp[1], wp[2], xp[0], xp[1], xp[2]);
        }
        duxin_s[d][hr] = v;
    }

    // ---- Phase A1: xin = in_proj(x_t) for own 12 channels (uniform weights) ----
    {
        const float4* xp = (const float4*)(x + ((size_t)b * SEQ + (t0 + t)) * DM);
        float4 r0 = xp[0], r1 = xp[1], r2 = xp[2];
#pragma unroll 4
        for (int i = 0; i < 12; ++i) {
            const float4* wp = (const float4*)(ipw + (dlo + i) * DM);
            duxin_s[dlo + i][t + 3] = dot12w(wp[0], wp[1], wp[2], r0, r1, r2);
        }
    }
    __syncthreads();

    // ---- Phase A2: causal conv + silu for own 12 channels ----
    float xc_reg[12];
#pragma unroll 4
    for (int i = 0; i < 12; ++i) {
        int d = dlo + i;
        const float4 c4 = *(const float4*)(cw + d * DC);
        float acc = cb[d];
        acc = fmaf(c4.x, duxin_s[d][t + 0], acc);
        acc = fmaf(c4.y, duxin_s[d][t + 1], acc);
        acc = fmaf(c4.z, duxin_s[d][t + 2], acc);
        acc = fmaf(c4.w, duxin_s[d][t + 3], acc);
        float v = silu_f(acc);
        xc_reg[i] = v;
        dtxc_s[d][t] = v;
    }
    __syncthreads();

    // ---- Phase B: x_proj rows 10*half..10*half+9; own-half xc from regs ----
    {
        float xcv[DI];
#pragma unroll
        for (int i = 0; i < 12; ++i) xcv[dlo + i] = xc_reg[i];
#pragma unroll
        for (int i = 0; i < 12; ++i) xcv[olo + i] = dtxc_s[olo + i][t];
#pragma unroll 2
        for (int q = 0; q < 10; ++q) {
            int r = half_u * 10 + q;                 // wave-uniform row
            const float4* wr = (const float4*)(xpw + r * DI);
            float s = 0.f;
#pragma unroll
            for (int c = 0; c < 6; ++c) {
                float4 w4 = wr[c];
                s = fmaf(w4.x, xcv[4 * c + 0], s);
                s = fmaf(w4.y, xcv[4 * c + 1], s);
                s = fmaf(w4.z, xcv[4 * c + 2], s);
                s = fmaf(w4.w, xcv[4 * c + 3], s);
            }
            if (r < DTR) dtr_s[r][t] = s;
            else         Bs_s[r - DTR][t] = s;
        }
    }
    __syncthreads();

    // ---- Phase C: dt = softplus(dt_raw @ dpw^T + dpb); dt,du -> LDS ----
    {
        float d0 = dtr_s[0][t], d1 = dtr_s[1][t], d2 = dtr_s[2][t], d3 = dtr_s[3][t];
#pragma unroll 4
        for (int i = 0; i < 12; ++i) {
            int d = dlo + i;
            const float4 w4 = *(const float4*)(dpw + d * DTR);
            float sv = dpb[d];
            sv = fmaf(d0, w4.x, sv); sv = fmaf(d1, w4.y, sv);
            sv = fmaf(d2, w4.z, sv); sv = fmaf(d3, w4.w, sv);
            float dt = softplus_f(sv);
            dtxc_s[d][t] = dt;               // overwrites xc (dead after B)
            duxin_s[d][t] = dt * xc_reg[i];  // du (xin dead after A2)
        }
    }
    __syncthreads();

    // ---- Scan: 3 pairs × 2 independent 32-step half-chains (6-way ILP) ----
    {
        const int s_ = tid & 15;
        const int dq = tid >> 4;             // 0..7 across both waves
        float sdtL[3], sdtH[3], baL[3], baH[3];
#pragma unroll
        for (int p = 0; p < 3; ++p) { sdtL[p] = sdtH[p] = baL[p] = baH[p] = 0.f; }
        const float* dt_r0 = &dtxc_s[dq][0];
        const float* du_r0 = &duxin_s[dq][0];
#pragma unroll 2
        for (int i = 0; i < 8; ++i) {
            const float4 BL = *(const float4*)&Bs_s[s_][4 * i];
            const float4 BH = *(const float4*)&Bs_s[s_][32 + 4 * i];
#pragma unroll
            for (int p = 0; p < 3; ++p) {
                const float4 dL = *(const float4*)(dt_r0 + p * 8 * LP + 4 * i);
                const float4 dH = *(const float4*)(dt_r0 + p * 8 * LP + 32 + 4 * i);
                const float4 uL = *(const float4*)(du_r0 + p * 8 * LP + 4 * i);
                const float4 uH = *(const float4*)(du_r0 + p * 8 * LP + 32 + 4 * i);
                float a;
                a = EXP2F(dL.x * Ap2[p]); baL[p] = fmaf(a, baL[p], uL.x * BL.x); sdtL[p] += dL.x;
                a = EXP2F(dH.x * Ap2[p]); baH[p] = fmaf(a, baH[p], uH.x * BH.x); sdtH[p] += dH.x;
                a = EXP2F(dL.y * Ap2[p]); baL[p] = fmaf(a, baL[p], uL.y * BL.y); sdtL[p] += dL.y;
                a = EXP2F(dH.y * Ap2[p]); baH[p] = fmaf(a, baH[p], uH.y * BH.y); sdtH[p] += dH.y;
                a = EXP2F(dL.z * Ap2[p]); baL[p] = fmaf(a, baL[p], uL.z * BL.z); sdtL[p] += dL.z;
                a = EXP2F(dH.z * Ap2[p]); baH[p] = fmaf(a, baH[p], uH.z * BH.z); sdtH[p] += dH.z;
                a = EXP2F(dL.w * Ap2[p]); baL[p] = fmaf(a, baL[p], uL.w * BL.w); sdtL[p] += dL.w;
                a = EXP2F(dH.w * Ap2[p]); baH[p] = fmaf(a, baH[p], uH.w * BH.w); sdtH[p] += dH.w;
            }
        }
        // compose: lo (t=0..31) then hi (t=32..63)
        const size_t base = (size_t)blockIdx.x * (DI * DS);
#pragma unroll
        for (int p = 0; p < 3; ++p) {
            float aH = EXP2F(Ap2[p] * sdtH[p]);
            segA[base + 128 * p + tid] = EXP2F(Ap2[p] * (sdtL[p] + sdtH[p]));
            segB[base + 128 * p + tid] = fmaf(aH, baL[p], baH[p]);
        }
    }
}

// One block per batch: combine 32 segments + tiny epilogue.
__global__ __launch_bounds__(384) void finish_kernel(
    const float* __restrict__ segA, const float* __restrict__ segB,
    const float* __restrict__ x, const float* __restrict__ ipw,
    const float* __restrict__ cw, const float* __restrict__ cb,
    const float* __restrict__ xpw, const float* __restrict__ Dv,
    const float* __restrict__ opw, const float* __restrict__ fcw,
    const float* __restrict__ fcb, float* __restrict__ out)
{
    int b = blockIdx.x, tid = threadIdx.x;

    float h = 0.f;
#pragma unroll
    for (int g = 0; g < NSEG; ++g) {
        size_t o = ((size_t)(b * NSEG + g)) * (DI * DS) + tid;
        h = fmaf(segA[o], h, segB[o]);
    }

    __shared__ float h_sh[DI * DS];
    __shared__ float xcl[DI], CL[DS], zv[DI], yv[DI], ov[DM];
    h_sh[tid] = h;

    const float* xr = x + ((size_t)b * SEQ + SEQ - 1) * DM;
    if (tid < DI) {
        float acc = cb[tid];
#pragma unroll
        for (int k = 0; k < DC; ++k) {
            const float* row = x + ((size_t)b * SEQ + (SEQ - DC + k)) * DM;
            float xin = 0.f;
#pragma unroll
            for (int m = 0; m < DM; ++m) xin = fmaf(row[m], ipw[tid * DM + m], xin);
            acc = fmaf(xin, cw[tid * DC + k], acc);
        }
        xcl[tid] = silu_f(acc);
        float s = 0.f;
#pragma unroll
        for (int m = 0; m < DM; ++m) s = fmaf(xr[m], ipw[(DI + tid) * DM + m], s);
        zv[tid] = s;
    }
    __syncthreads();

    if (tid < DS) {
        float s = 0.f;
#pragma unroll
        for (int d = 0; d < DI; ++d) s = fmaf(xcl[d], xpw[(DTR + DS + tid) * DI + d], s);
        CL[tid] = s;
    }
    __syncthreads();

    if (tid < DI) {
        float y = 0.f;
#pragma unroll
        for (int s2 = 0; s2 < DS; ++s2) y = fmaf(h_sh[tid * DS + s2], CL[s2], y);
        y = fmaf(xcl[tid], Dv[tid], y);
        yv[tid] = y * silu_f(zv[tid]);
    }
    __syncthreads();

    if (tid < DM) {
        float s = 0.f;
#pragma unroll
        for (int d = 0; d < DI; ++d) s = fmaf(yv[d], opw[tid * DI + d], s);
        ov[tid] = s;
    }
    __syncthreads();

    if (tid == 0) {
        float s = fcb[0];
#pragma unroll
        for (int e = 0; e < DM; ++e) s = fmaf(ov[e], fcw[e], s);
        out[b] = s;
    }
}

extern "C" void kernel_launch(void* const* d_in, const int* in_sizes, int n_in,
                              void* d_out, int out_size, void* d_ws, size_t ws_size,
                              hipStream_t stream)
{
    const float* x   = (const float*)d_in[0];
    const float* ipw = (const float*)d_in[1];
    const float* cw  = (const float*)d_in[2];
    const float* cb  = (const float*)d_in[3];
    const float* xpw = (const float*)d_in[4];
    const float* dpw = (const float*)d_in[5];
    const float* dpb = (const float*)d_in[6];
    const float* Al  = (const float*)d_in[7];
    const float* Dv  = (const float*)d_in[8];
    const float* opw = (const float*)d_in[9];
    const float* fcw = (const float*)d_in[10];
    const float* fcb = (const float*)d_in[11];

    float* segA = (float*)d_ws;                            // [B*NSEG][384]
    float* segB = segA + (size_t)B_SZ * NSEG * DI * DS;

    fused2_kernel<<<B_SZ * NSEG, 128, 0, stream>>>(
        x, ipw, cw, cb, xpw, dpw, dpb, Al, segA, segB);
    finish_kernel<<<B_SZ, 384, 0, stream>>>(
        segA, segB, x, ipw, cw, cb, xpw, Dv, opw, fcw, fcb, (float*)d_out);
}